// Round 5
// baseline (275.590 us; speedup 1.0000x reference)
//
#include <hip/hip_runtime.h>
#include <hip/hip_bf16.h>
#include <stdint.h>

#define NUM_NODES 100000
#define NUM_EDGES 50000
#define NUM_CONN  800000
#define IN_DIM    256
#define HIDDEN    128
#define EDGE_DIM  17
#define PAD       64

typedef __bf16 bf16x8 __attribute__((ext_vector_type(8)));
typedef float  f32x4  __attribute__((ext_vector_type(4)));

// ---------------- ws layout ----------------
// P     : bf16 [NUM_NODES][HIDDEN]   25,600,000 B @ 0
// counts: int  [NUM_EDGES]              200,000 B @ 25,600,000
// slots : int  [NUM_EDGES][PAD]      12,800,000 B @ 25,800,000
// W1F   : bf16 frag-major [8][8][64][8]  65,536 B @ 38,600,000
// W2F   : bf16 frag-major [4][2][64][8]   8,192 B @ 38,665,536
// r     : bf16 [NUM_EDGES][HIDDEN]   12,800,000 B @ 38,673,728

// Zero counts + pack W1/W2 into MFMA B-fragment-major bf16 (one launch).
__global__ void prep_kernel(const float* __restrict__ W1, const float* __restrict__ W2,
                            __bf16* __restrict__ w1f, __bf16* __restrict__ w2f,
                            int* __restrict__ counts) {
    int i = blockIdx.x * 256 + threadIdx.x;   // grid 196*256 = 50176
    if (i < NUM_EDGES) counts[i] = 0;
    if (i < 4096) {            // W1F[kc2][t][lane][ki]
        int lane = i & 63, t = (i >> 6) & 7, kc2 = i >> 9;
        int m = lane & 15, q = lane >> 4;
        int n = t * 16 + m;
        int kbase = kc2 * 32 + q * 8;
        __bf16* dst = w1f + (size_t)i * 8;
        #pragma unroll
        for (int ki = 0; ki < 8; ++ki)
            dst[ki] = (__bf16)W1[(size_t)(kbase + ki) * HIDDEN + n];
    } else if (i < 4608) {     // W2F[ks][t][lane][ki], n>=17 zero-padded
        int f = i - 4096;
        int lane = f & 63, t = (f >> 6) & 1, ks = f >> 7;
        int m = lane & 15, q = lane >> 4;
        int n = t * 16 + m;
        int kbase = ks * 32 + q * 8;
        __bf16* dst = w2f + (size_t)f * 8;
        #pragma unroll
        for (int ki = 0; ki < 8; ++ki)
            dst[ki] = (n < EDGE_DIM) ? (__bf16)W2[(size_t)(kbase + ki) * EDGE_DIM + n]
                                     : (__bf16)0.0f;
    }
}

__global__ void bucket_kernel(const int* __restrict__ idx,
                              int* __restrict__ counts, int* __restrict__ slots) {
    // int64 path: thread handles 2 connections via int4 loads
    int i = blockIdx.x * 256 + threadIdx.x;
    if (i >= NUM_CONN / 2) return;
    int4 vn = ((const int4*)idx)[i];
    int4 ve = ((const int4*)(idx + 2 * NUM_CONN))[i];
    int p0 = atomicAdd(&counts[ve.x], 1);
    if (p0 < PAD) slots[(size_t)ve.x * PAD + p0] = vn.x;
    int p1 = atomicAdd(&counts[ve.z], 1);
    if (p1 < PAD) slots[(size_t)ve.z * PAD + p1] = vn.z;
}

__global__ void bucket_kernel_i32(const int* __restrict__ idx,
                                  int* __restrict__ counts, int* __restrict__ slots) {
    int i = blockIdx.x * 256 + threadIdx.x;
    if (i >= NUM_CONN) return;
    int node = idx[i];
    int edge = idx[NUM_CONN + i];
    int pos = atomicAdd(&counts[edge], 1);
    if (pos < PAD) slots[(size_t)edge * PAD + pos] = node;
}

// P[m][n] = sum_k nf[m][k] * W1[k][n]. No LDS: B-frags stream from L2.
// 2 m-tiles/wave, 128 rows/block, grid 782.
__global__ __launch_bounds__(256) void proj_kernel(const float* __restrict__ nf,
                                                   const __bf16* __restrict__ w1f,
                                                   __bf16* __restrict__ pbf) {
    const int wave = threadIdx.x >> 6;
    const int lane = threadIdx.x & 63;
    const int m = lane & 15, q = lane >> 4;
    const int rowbase = blockIdx.x * 128 + wave * 32;
    const bf16x8* __restrict__ frag = (const bf16x8*)w1f;

    f32x4 acc[2][8];
    #pragma unroll
    for (int mt = 0; mt < 2; ++mt)
        #pragma unroll
        for (int t = 0; t < 8; ++t) acc[mt][t] = (f32x4){0.f, 0.f, 0.f, 0.f};

    const float* ap[2];
    #pragma unroll
    for (int mt = 0; mt < 2; ++mt) {
        int r = rowbase + mt * 16 + m;
        if (r >= NUM_NODES) r = NUM_NODES - 1;
        ap[mt] = nf + (size_t)r * IN_DIM + q * 8;
    }

    #pragma unroll
    for (int kc2 = 0; kc2 < 8; ++kc2) {
        bf16x8 b[8];
        #pragma unroll
        for (int t = 0; t < 8; ++t) b[t] = frag[(kc2 * 8 + t) * 64 + lane];
        #pragma unroll
        for (int mt = 0; mt < 2; ++mt) {
            float4 f0 = *(const float4*)(ap[mt] + kc2 * 32);
            float4 f1 = *(const float4*)(ap[mt] + kc2 * 32 + 4);
            bf16x8 a;
            a[0] = (__bf16)f0.x; a[1] = (__bf16)f0.y;
            a[2] = (__bf16)f0.z; a[3] = (__bf16)f0.w;
            a[4] = (__bf16)f1.x; a[5] = (__bf16)f1.y;
            a[6] = (__bf16)f1.z; a[7] = (__bf16)f1.w;
            #pragma unroll
            for (int t = 0; t < 8; ++t)
                acc[mt][t] = __builtin_amdgcn_mfma_f32_16x16x32_bf16(a, b[t], acc[mt][t], 0, 0, 0);
        }
    }

    #pragma unroll
    for (int mt = 0; mt < 2; ++mt) {
        int ob = rowbase + mt * 16 + q * 4;
        #pragma unroll
        for (int t = 0; t < 8; ++t)
            #pragma unroll
            for (int r = 0; r < 4; ++r) {
                int orow = ob + r;
                if (orow < NUM_NODES)
                    pbf[(size_t)orow * HIDDEN + t * 16 + m] = (__bf16)acc[mt][t][r];
            }
    }
}

// 4 edges per wave, 16 lanes per edge, 4 rows/edge in flight.
// Lane g (= lane&15) owns hidden dims 8g..8g+7 of its edge.
__global__ __launch_bounds__(256) void edge_kernel(const uint4* __restrict__ p4,
        const int* __restrict__ counts, const int* __restrict__ slots,
        const float* __restrict__ b1, const float* __restrict__ ln_g,
        const float* __restrict__ ln_b, uint4* __restrict__ rws) {
    const int wave = threadIdx.x >> 6;
    const int lane = threadIdx.x & 63;
    const int g = lane & 15, ge = lane >> 4;
    const int e = blockIdx.x * 16 + wave * 4 + ge;

    const int c = counts[e];
    const int cc = c < PAD ? c : PAD;
    const float inv = 1.0f / (float)(c > 0 ? c : 1);

    float acc[8];
    #pragma unroll
    for (int d = 0; d < 8; ++d) acc[d] = 0.f;

    for (int c0 = 0; c0 < cc; c0 += 16) {
        // 16 slots of this chunk live across the group's 16 lanes
        int slv = slots[(size_t)e * PAD + c0 + g];
        int lim = cc - c0; if (lim > 16) lim = 16;
        if (lim == 16) {
            #pragma unroll
            for (int k0 = 0; k0 < 16; k0 += 4) {
                uint4 u[4];
                #pragma unroll
                for (int k = 0; k < 4; ++k) {
                    int nd = __shfl(slv, ge * 16 + k0 + k, 64);
                    u[k] = p4[(size_t)nd * 16 + g];
                }
                #pragma unroll
                for (int k = 0; k < 4; ++k) {
                    acc[0] += __uint_as_float(u[k].x << 16);
                    acc[1] += __uint_as_float(u[k].x & 0xffff0000u);
                    acc[2] += __uint_as_float(u[k].y << 16);
                    acc[3] += __uint_as_float(u[k].y & 0xffff0000u);
                    acc[4] += __uint_as_float(u[k].z << 16);
                    acc[5] += __uint_as_float(u[k].z & 0xffff0000u);
                    acc[6] += __uint_as_float(u[k].w << 16);
                    acc[7] += __uint_as_float(u[k].w & 0xffff0000u);
                }
            }
        } else {
            for (int k0 = 0; k0 < lim; k0 += 4) {
                uint4 u[4];
                unsigned okm[4];
                #pragma unroll
                for (int k = 0; k < 4; ++k) {
                    int nd = __shfl(slv, ge * 16 + k0 + k, 64);
                    nd = ((unsigned)nd < NUM_NODES) ? nd : 0;
                    u[k] = p4[(size_t)nd * 16 + g];
                    okm[k] = (k0 + k < lim) ? 0xffffffffu : 0u;
                }
                #pragma unroll
                for (int k = 0; k < 4; ++k) {
                    uint4 v = u[k];
                    v.x &= okm[k]; v.y &= okm[k]; v.z &= okm[k]; v.w &= okm[k];
                    acc[0] += __uint_as_float(v.x << 16);
                    acc[1] += __uint_as_float(v.x & 0xffff0000u);
                    acc[2] += __uint_as_float(v.y << 16);
                    acc[3] += __uint_as_float(v.y & 0xffff0000u);
                    acc[4] += __uint_as_float(v.z << 16);
                    acc[5] += __uint_as_float(v.z & 0xffff0000u);
                    acc[6] += __uint_as_float(v.w << 16);
                    acc[7] += __uint_as_float(v.w & 0xffff0000u);
                }
            }
        }
    }

    float4 bA = ((const float4*)b1)[2 * g];
    float4 bB = ((const float4*)b1)[2 * g + 1];
    float h[8];
    h[0] = acc[0] * inv + bA.x; h[1] = acc[1] * inv + bA.y;
    h[2] = acc[2] * inv + bA.z; h[3] = acc[3] * inv + bA.w;
    h[4] = acc[4] * inv + bB.x; h[5] = acc[5] * inv + bB.y;
    h[6] = acc[6] * inv + bB.z; h[7] = acc[7] * inv + bB.w;

    float s = 0.f;
    #pragma unroll
    for (int d = 0; d < 8; ++d) s += h[d];
    #pragma unroll
    for (int off = 8; off > 0; off >>= 1) s += __shfl_xor(s, off, 64);
    float mu = s * (1.0f / 128.0f);

    float dv[8], vv = 0.f;
    #pragma unroll
    for (int d = 0; d < 8; ++d) { dv[d] = h[d] - mu; vv += dv[d] * dv[d]; }
    #pragma unroll
    for (int off = 8; off > 0; off >>= 1) vv += __shfl_xor(vv, off, 64);
    float rs = rsqrtf(vv * (1.0f / 128.0f) + 1e-5f);

    float4 gA = ((const float4*)ln_g)[2 * g];
    float4 gB = ((const float4*)ln_g)[2 * g + 1];
    float4 eA = ((const float4*)ln_b)[2 * g];
    float4 eB = ((const float4*)ln_b)[2 * g + 1];
    float gg[8] = {gA.x, gA.y, gA.z, gA.w, gB.x, gB.y, gB.z, gB.w};
    float ee[8] = {eA.x, eA.y, eA.z, eA.w, eB.x, eB.y, eB.z, eB.w};
    union { __bf16 b[8]; uint4 u; } pk;
    #pragma unroll
    for (int d = 0; d < 8; ++d) {
        float r = dv[d] * rs * gg[d] + ee[d];
        pk.b[d] = (__bf16)(r > 0.f ? r : 0.f);
    }
    rws[(size_t)e * 16 + g] = pk.u;
}

// out[e][j] = r[e]·W2[:,j] + b2[j] via MFMA: [50K x 128] @ [128 x 32pad].
__global__ __launch_bounds__(256) void out_kernel(const __bf16* __restrict__ rws,
        const __bf16* __restrict__ w2f, const float* __restrict__ b2,
        float* __restrict__ out) {
    __shared__ __align__(16) __bf16 lds[4096];   // 8 KB
    {
        const uint4* s = (const uint4*)w2f;
        uint4* d = (uint4*)lds;
        #pragma unroll
        for (int i = threadIdx.x; i < 512; i += 256) d[i] = s[i];
    }
    __syncthreads();
    const int wave = threadIdx.x >> 6;
    const int lane = threadIdx.x & 63;
    const int tile = blockIdx.x * 4 + wave;
    if (tile >= NUM_EDGES / 16) return;
    const int m = lane & 15, q = lane >> 4;
    const bf16x8* frag = (const bf16x8*)lds;
    const __bf16* arow = rws + ((size_t)tile * 16 + m) * HIDDEN + q * 8;

    f32x4 acc0 = (f32x4){0.f, 0.f, 0.f, 0.f};
    f32x4 acc1 = (f32x4){0.f, 0.f, 0.f, 0.f};
    #pragma unroll
    for (int s = 0; s < 4; ++s) {
        bf16x8 a = *(const bf16x8*)(arow + s * 32);
        acc0 = __builtin_amdgcn_mfma_f32_16x16x32_bf16(a, frag[(s * 2 + 0) * 64 + lane], acc0, 0, 0, 0);
        acc1 = __builtin_amdgcn_mfma_f32_16x16x32_bf16(a, frag[(s * 2 + 1) * 64 + lane], acc1, 0, 0, 0);
    }
    int rowb = tile * 16 + q * 4;
    float bm = b2[m];
    #pragma unroll
    for (int r = 0; r < 4; ++r) {
        out[(size_t)(rowb + r) * EDGE_DIM + m] = acc0[r] + bm;
        if (m == 0) out[(size_t)(rowb + r) * EDGE_DIM + 16] = acc1[r] + b2[16];
    }
}

extern "C" void kernel_launch(void* const* d_in, const int* in_sizes, int n_in,
                              void* d_out, int out_size, void* d_ws, size_t ws_size,
                              hipStream_t stream) {
    const float* nf  = (const float*)d_in[0];
    const int*   idx = (const int*)d_in[1];
    const float* W1  = (const float*)d_in[2];
    const float* b1  = (const float*)d_in[3];
    const float* g   = (const float*)d_in[4];
    const float* be  = (const float*)d_in[5];
    const float* W2  = (const float*)d_in[6];
    const float* b2  = (const float*)d_in[7];
    float* out = (float*)d_out;

    char* ws = (char*)d_ws;
    __bf16* P      = (__bf16*)ws;
    int*    counts = (int*)(ws + 25600000);
    int*    slots  = (int*)(ws + 25800000);
    __bf16* W1F    = (__bf16*)(ws + 38600000);
    __bf16* W2F    = (__bf16*)(ws + 38665536);
    __bf16* R      = (__bf16*)(ws + 38673728);

    int stride = (in_sizes[1] == 2 * NUM_CONN) ? 1 : 2;

    prep_kernel<<<196, 256, 0, stream>>>(W1, W2, W1F, W2F, counts);
    if (stride == 2)
        bucket_kernel<<<(NUM_CONN / 2 + 255) / 256, 256, 0, stream>>>(idx, counts, slots);
    else
        bucket_kernel_i32<<<(NUM_CONN + 255) / 256, 256, 0, stream>>>(idx, counts, slots);
    proj_kernel<<<(NUM_NODES + 127) / 128, 256, 0, stream>>>(nf, W1F, P);
    edge_kernel<<<NUM_EDGES / 16, 256, 0, stream>>>((const uint4*)P, counts, slots,
                                                    b1, g, be, (uint4*)R);
    out_kernel<<<(NUM_EDGES / 16 + 3) / 4, 256, 0, stream>>>(R, W2F, b2, out);
}

// Round 6
// 252.651 us; speedup vs baseline: 1.0908x; 1.0908x over previous
//
#include <hip/hip_runtime.h>
#include <hip/hip_bf16.h>
#include <stdint.h>

#define NUM_NODES 100000
#define NUM_EDGES 50000
#define NUM_CONN  800000
#define IN_DIM    256
#define HIDDEN    128
#define EDGE_DIM  17
#define PAD       64

typedef __bf16 bf16x8 __attribute__((ext_vector_type(8)));
typedef float  f32x4  __attribute__((ext_vector_type(4)));

// ---------------- ws layout ----------------
// P     : bf16 [NUM_NODES][HIDDEN]   25,600,000 B @ 0
// counts: int  [NUM_EDGES]              200,000 B @ 25,600,000
// slots : int  [NUM_EDGES][PAD]      12,800,000 B @ 25,800,000
// W1F   : bf16 frag-major [8][8][64][8]  65,536 B @ 38,600,000
// W2F   : bf16 frag-major [4][2][64][8]   8,192 B @ 38,665,536

// Zero counts + pack W1/W2 into MFMA B-fragment-major bf16 (one launch).
__global__ void prep_kernel(const float* __restrict__ W1, const float* __restrict__ W2,
                            __bf16* __restrict__ w1f, __bf16* __restrict__ w2f,
                            int* __restrict__ counts) {
    int i = blockIdx.x * 256 + threadIdx.x;   // grid 196*256 = 50176
    if (i < NUM_EDGES) counts[i] = 0;
    if (i < 4096) {            // W1F[kc2][t][lane][ki]
        int lane = i & 63, t = (i >> 6) & 7, kc2 = i >> 9;
        int m = lane & 15, q = lane >> 4;
        int n = t * 16 + m;
        int kbase = kc2 * 32 + q * 8;
        __bf16* dst = w1f + (size_t)i * 8;
        #pragma unroll
        for (int ki = 0; ki < 8; ++ki)
            dst[ki] = (__bf16)W1[(size_t)(kbase + ki) * HIDDEN + n];
    } else if (i < 4608) {     // W2F[ks][t][lane][ki], n>=17 zero-padded
        int f = i - 4096;
        int lane = f & 63, t = (f >> 6) & 1, ks = f >> 7;
        int m = lane & 15, q = lane >> 4;
        int n = t * 16 + m;
        int kbase = ks * 32 + q * 8;
        __bf16* dst = w2f + (size_t)f * 8;
        #pragma unroll
        for (int ki = 0; ki < 8; ++ki)
            dst[ki] = (n < EDGE_DIM) ? (__bf16)W2[(size_t)(kbase + ki) * EDGE_DIM + n]
                                     : (__bf16)0.0f;
    }
}

// Fused bucket + proj. blockIdx % 3 == 2 -> proj role (782 blocks);
// else bucket role (1564 blocks, last one idles via thread guard).
// Bucket's memory-stalled waves hide proj's load latency and vice versa.
#define FRONT_BLOCKS 2346
__global__ __launch_bounds__(256) void front_kernel(const int* __restrict__ idx,
        int* __restrict__ counts, int* __restrict__ slots,
        const float* __restrict__ nf, const __bf16* __restrict__ w1f,
        __bf16* __restrict__ pbf) {
    if (blockIdx.x % 3 != 2) {
        // ---- bucket role: 2 connections per thread, int2 loads ----
        int b = blockIdx.x - blockIdx.x / 3;
        int i = b * 256 + threadIdx.x;
        if (i < NUM_CONN / 2) {
            int2 vn = ((const int2*)idx)[i];
            int2 ve = ((const int2*)(idx + NUM_CONN))[i];
            int p0 = atomicAdd(&counts[ve.x], 1);
            if (p0 < PAD) slots[(size_t)ve.x * PAD + p0] = vn.x;
            int p1 = atomicAdd(&counts[ve.y], 1);
            if (p1 < PAD) slots[(size_t)ve.y * PAD + p1] = vn.y;
        }
        return;
    }
    // ---- proj role: P[m][n] = sum_k nf[m][k] * W1[k][n], no LDS ----
    const int p_idx = blockIdx.x / 3;            // 0..781
    const int wave = threadIdx.x >> 6;
    const int lane = threadIdx.x & 63;
    const int m = lane & 15, q = lane >> 4;
    const int rowbase = p_idx * 128 + wave * 32;
    const bf16x8* __restrict__ frag = (const bf16x8*)w1f;

    f32x4 acc[2][8];
    #pragma unroll
    for (int mt = 0; mt < 2; ++mt)
        #pragma unroll
        for (int t = 0; t < 8; ++t) acc[mt][t] = (f32x4){0.f, 0.f, 0.f, 0.f};

    const float* ap[2];
    #pragma unroll
    for (int mt = 0; mt < 2; ++mt) {
        int r = rowbase + mt * 16 + m;
        if (r >= NUM_NODES) r = NUM_NODES - 1;
        ap[mt] = nf + (size_t)r * IN_DIM + q * 8;
    }

    #pragma unroll
    for (int kc2 = 0; kc2 < 8; ++kc2) {
        bf16x8 b[8];
        #pragma unroll
        for (int t = 0; t < 8; ++t) b[t] = frag[(kc2 * 8 + t) * 64 + lane];
        #pragma unroll
        for (int mt = 0; mt < 2; ++mt) {
            float4 f0 = *(const float4*)(ap[mt] + kc2 * 32);
            float4 f1 = *(const float4*)(ap[mt] + kc2 * 32 + 4);
            bf16x8 a;
            a[0] = (__bf16)f0.x; a[1] = (__bf16)f0.y;
            a[2] = (__bf16)f0.z; a[3] = (__bf16)f0.w;
            a[4] = (__bf16)f1.x; a[5] = (__bf16)f1.y;
            a[6] = (__bf16)f1.z; a[7] = (__bf16)f1.w;
            #pragma unroll
            for (int t = 0; t < 8; ++t)
                acc[mt][t] = __builtin_amdgcn_mfma_f32_16x16x32_bf16(a, b[t], acc[mt][t], 0, 0, 0);
        }
    }

    #pragma unroll
    for (int mt = 0; mt < 2; ++mt) {
        int ob = rowbase + mt * 16 + q * 4;
        #pragma unroll
        for (int t = 0; t < 8; ++t)
            #pragma unroll
            for (int r = 0; r < 4; ++r) {
                int orow = ob + r;
                if (orow < NUM_NODES)
                    pbf[(size_t)orow * HIDDEN + t * 16 + m] = (__bf16)acc[mt][t][r];
            }
    }
}

// 4 edges/wave, 16 lanes/edge gather + LN + ReLU, then the block's 16 edges
// (= one MFMA tile) go through LDS and wave 0 computes out = r@W2 + b2.
__global__ __launch_bounds__(256) void edge_kernel(const uint4* __restrict__ p4,
        const int* __restrict__ counts, const int* __restrict__ slots,
        const float* __restrict__ b1, const float* __restrict__ ln_g,
        const float* __restrict__ ln_b, const __bf16* __restrict__ w2f,
        const float* __restrict__ b2, float* __restrict__ out) {
    __shared__ __align__(16) uint4 lds_r[256];   // 16 edges x 128 bf16 = 4 KB
    const int wave = threadIdx.x >> 6;
    const int lane = threadIdx.x & 63;
    const int g = lane & 15, ge = lane >> 4;
    const int el = wave * 4 + ge;                 // edge-local 0..15
    const int e = blockIdx.x * 16 + el;

    const int c = counts[e];
    const int cc = c < PAD ? c : PAD;
    const float inv = 1.0f / (float)(c > 0 ? c : 1);

    float acc[8];
    #pragma unroll
    for (int d = 0; d < 8; ++d) acc[d] = 0.f;

    for (int c0 = 0; c0 < cc; c0 += 16) {
        int slv = slots[(size_t)e * PAD + c0 + g];
        int lim = cc - c0; if (lim > 16) lim = 16;
        if (lim == 16) {
            #pragma unroll
            for (int k0 = 0; k0 < 16; k0 += 4) {
                uint4 u[4];
                #pragma unroll
                for (int k = 0; k < 4; ++k) {
                    int nd = __shfl(slv, ge * 16 + k0 + k, 64);
                    u[k] = p4[(size_t)nd * 16 + g];
                }
                #pragma unroll
                for (int k = 0; k < 4; ++k) {
                    acc[0] += __uint_as_float(u[k].x << 16);
                    acc[1] += __uint_as_float(u[k].x & 0xffff0000u);
                    acc[2] += __uint_as_float(u[k].y << 16);
                    acc[3] += __uint_as_float(u[k].y & 0xffff0000u);
                    acc[4] += __uint_as_float(u[k].z << 16);
                    acc[5] += __uint_as_float(u[k].z & 0xffff0000u);
                    acc[6] += __uint_as_float(u[k].w << 16);
                    acc[7] += __uint_as_float(u[k].w & 0xffff0000u);
                }
            }
        } else {
            for (int k0 = 0; k0 < lim; k0 += 4) {
                uint4 u[4];
                unsigned okm[4];
                #pragma unroll
                for (int k = 0; k < 4; ++k) {
                    int nd = __shfl(slv, ge * 16 + k0 + k, 64);
                    nd = ((unsigned)nd < NUM_NODES) ? nd : 0;
                    u[k] = p4[(size_t)nd * 16 + g];
                    okm[k] = (k0 + k < lim) ? 0xffffffffu : 0u;
                }
                #pragma unroll
                for (int k = 0; k < 4; ++k) {
                    uint4 v = u[k];
                    v.x &= okm[k]; v.y &= okm[k]; v.z &= okm[k]; v.w &= okm[k];
                    acc[0] += __uint_as_float(v.x << 16);
                    acc[1] += __uint_as_float(v.x & 0xffff0000u);
                    acc[2] += __uint_as_float(v.y << 16);
                    acc[3] += __uint_as_float(v.y & 0xffff0000u);
                    acc[4] += __uint_as_float(v.z << 16);
                    acc[5] += __uint_as_float(v.z & 0xffff0000u);
                    acc[6] += __uint_as_float(v.w << 16);
                    acc[7] += __uint_as_float(v.w & 0xffff0000u);
                }
            }
        }
    }

    float4 bA = ((const float4*)b1)[2 * g];
    float4 bB = ((const float4*)b1)[2 * g + 1];
    float h[8];
    h[0] = acc[0] * inv + bA.x; h[1] = acc[1] * inv + bA.y;
    h[2] = acc[2] * inv + bA.z; h[3] = acc[3] * inv + bA.w;
    h[4] = acc[4] * inv + bB.x; h[5] = acc[5] * inv + bB.y;
    h[6] = acc[6] * inv + bB.z; h[7] = acc[7] * inv + bB.w;

    float s = 0.f;
    #pragma unroll
    for (int d = 0; d < 8; ++d) s += h[d];
    #pragma unroll
    for (int off = 8; off > 0; off >>= 1) s += __shfl_xor(s, off, 64);
    float mu = s * (1.0f / 128.0f);

    float dv[8], vv = 0.f;
    #pragma unroll
    for (int d = 0; d < 8; ++d) { dv[d] = h[d] - mu; vv += dv[d] * dv[d]; }
    #pragma unroll
    for (int off = 8; off > 0; off >>= 1) vv += __shfl_xor(vv, off, 64);
    float rs = rsqrtf(vv * (1.0f / 128.0f) + 1e-5f);

    float4 gA = ((const float4*)ln_g)[2 * g];
    float4 gB = ((const float4*)ln_g)[2 * g + 1];
    float4 eA = ((const float4*)ln_b)[2 * g];
    float4 eB = ((const float4*)ln_b)[2 * g + 1];
    float gg[8] = {gA.x, gA.y, gA.z, gA.w, gB.x, gB.y, gB.z, gB.w};
    float ee[8] = {eA.x, eA.y, eA.z, eA.w, eB.x, eB.y, eB.z, eB.w};
    union { __bf16 b[8]; uint4 u; } pk;
    #pragma unroll
    for (int d = 0; d < 8; ++d) {
        float r = dv[d] * rs * gg[d] + ee[d];
        pk.b[d] = (__bf16)(r > 0.f ? r : 0.f);
    }
    lds_r[el * 16 + g] = pk.u;
    __syncthreads();

    if (wave == 0) {   // out tile: [16 edges x 128] @ [128 x 32pad]
        const int m = lane & 15, q = lane >> 4;
        const __bf16* lr = (const __bf16*)lds_r;
        const bf16x8* fw = (const bf16x8*)w2f;
        f32x4 a0 = (f32x4){0.f, 0.f, 0.f, 0.f};
        f32x4 a1 = (f32x4){0.f, 0.f, 0.f, 0.f};
        #pragma unroll
        for (int ks = 0; ks < 4; ++ks) {
            bf16x8 a = *(const bf16x8*)(lr + m * 128 + ks * 32 + q * 8);
            a0 = __builtin_amdgcn_mfma_f32_16x16x32_bf16(a, fw[(ks * 2 + 0) * 64 + lane], a0, 0, 0, 0);
            a1 = __builtin_amdgcn_mfma_f32_16x16x32_bf16(a, fw[(ks * 2 + 1) * 64 + lane], a1, 0, 0, 0);
        }
        int rowb = blockIdx.x * 16 + q * 4;
        float bm = b2[m];
        float b16 = b2[16];
        #pragma unroll
        for (int r = 0; r < 4; ++r) {
            out[(size_t)(rowb + r) * EDGE_DIM + m] = a0[r] + bm;
            if (m == 0) out[(size_t)(rowb + r) * EDGE_DIM + 16] = a1[r] + b16;
        }
    }
}

extern "C" void kernel_launch(void* const* d_in, const int* in_sizes, int n_in,
                              void* d_out, int out_size, void* d_ws, size_t ws_size,
                              hipStream_t stream) {
    const float* nf  = (const float*)d_in[0];
    const int*   idx = (const int*)d_in[1];
    const float* W1  = (const float*)d_in[2];
    const float* b1  = (const float*)d_in[3];
    const float* g   = (const float*)d_in[4];
    const float* be  = (const float*)d_in[5];
    const float* W2  = (const float*)d_in[6];
    const float* b2  = (const float*)d_in[7];
    float* out = (float*)d_out;

    char* ws = (char*)d_ws;
    __bf16* P      = (__bf16*)ws;
    int*    counts = (int*)(ws + 25600000);
    int*    slots  = (int*)(ws + 25800000);
    __bf16* W1F    = (__bf16*)(ws + 38600000);
    __bf16* W2F    = (__bf16*)(ws + 38665536);

    prep_kernel<<<196, 256, 0, stream>>>(W1, W2, W1F, W2F, counts);
    front_kernel<<<FRONT_BLOCKS, 256, 0, stream>>>(idx, counts, slots, nf, W1F, P);
    edge_kernel<<<NUM_EDGES / 16, 256, 0, stream>>>((const uint4*)P, counts, slots,
                                                    b1, g, be, W2F, b2, out);
}